// Round 4
// baseline (152.085 us; speedup 1.0000x reference)
//
#include <hip/hip_runtime.h>
#include <hip/hip_bf16.h>

#define DEV __device__ __forceinline__

typedef unsigned short u16;
typedef __attribute__((ext_vector_type(8))) short bf16x8;
typedef __attribute__((ext_vector_type(4))) float f32x4;
typedef __attribute__((ext_vector_type(16))) float f32x16;
typedef __attribute__((ext_vector_type(4))) unsigned short us4;
typedef __attribute__((ext_vector_type(2))) unsigned u32x2;

DEV void gld_lds16(const void* g, void* l) {
  __builtin_amdgcn_global_load_lds((const __attribute__((address_space(1))) void*)g,
                                   (__attribute__((address_space(3))) void*)l, 16, 0, 0);
}

DEV u16 f2bf(float x) {  // RNE f32->bf16 (inputs finite)
  union { float f; unsigned u; } v; v.f = x;
  unsigned r = v.u + 0x7FFFu + ((v.u >> 16) & 1u);
  return (u16)(r >> 16);
}

DEV float ex2(float x) {  // 2^x
  float r; asm("v_exp_f32 %0, %1" : "=v"(r) : "v"(x)); return r;
}

DEV unsigned cvtpk(float a, float b) {  // [bf16(b)<<16 | bf16(a)]
  unsigned r; asm("v_cvt_pk_bf16_f32 %0, %1, %2" : "=v"(r) : "v"(a), "v"(b)); return r;
}

// ---------------- prep: cast x to bf16 ----------------
__global__ __launch_bounds__(256) void k_cast_x(const float* __restrict__ x, u16* __restrict__ xb) {
  int i = (blockIdx.x * 256 + threadIdx.x) * 4;
  const float4 v = *(const float4*)(x + i);
  us4 o; o.x = f2bf(v.x); o.y = f2bf(v.y); o.z = f2bf(v.z); o.w = f2bf(v.w);
  *(us4*)(xb + i) = o;
}

// ---------------- prep: transpose-pack weights to bf16 ----------------
__global__ __launch_bounds__(256) void k_prep_w(const float* __restrict__ Wq, const float* __restrict__ Wk,
                                                const float* __restrict__ Wv, const float* __restrict__ Wo,
                                                u16* __restrict__ wqkt, u16* __restrict__ wvt,
                                                u16* __restrict__ wot) {
  __shared__ float t[64][65];
  const int bb = blockIdx.x, tid = threadIdx.x;
  const float* src; u16* dst; int src_ld, dst_row0, dst_col0;
  if (bb < 768) {
    int which = bb >> 8, h = (bb >> 4) & 15, m0 = (bb & 15) * 64;
    const float* W = which == 0 ? Wq : (which == 1 ? Wk : Wv);
    src = W + h * 65536 + m0 * 64; src_ld = 64;
    dst = (which == 2) ? wvt : (wqkt + (which == 1 ? (1024 * 1024) : 0));
    dst_row0 = h * 64; dst_col0 = m0;
  } else {
    int t2 = bb - 768, mt = t2 >> 4, nt = t2 & 15;
    src = Wo + (size_t)(mt * 64) * 1024 + nt * 64; src_ld = 1024;
    dst = wot; dst_row0 = nt * 64; dst_col0 = mt * 64;
  }
  {
    int r = tid >> 2, c0 = (tid & 3) * 16;
    const float* s = src + (size_t)r * src_ld + c0;
#pragma unroll
    for (int q = 0; q < 4; ++q) {
      float4 v = *(const float4*)(s + q * 4);
      t[r][c0 + q * 4 + 0] = v.x; t[r][c0 + q * 4 + 1] = v.y;
      t[r][c0 + q * 4 + 2] = v.z; t[r][c0 + q * 4 + 3] = v.w;
    }
  }
  __syncthreads();
  {
    int d = tid >> 2, mb = (tid & 3) * 16;
    bf16x8 v0, v1;
#pragma unroll
    for (int e = 0; e < 8; ++e) {
      v0[e] = (short)f2bf(t[mb + e][d]);
      v1[e] = (short)f2bf(t[mb + 8 + e][d]);
    }
    u16* dp = dst + (size_t)(dst_row0 + d) * 1024 + dst_col0 + mb;
    *(bf16x8*)(dp) = v0;
    *(bf16x8*)(dp + 8) = v1;
  }
}

// ---------------- GEMM: C[M,N] = A[M,K] x Bt[N,K]^T (+bias, epilogue by MODE) ----------------
// MODE 0: out bf16 qk[4096,2048]; Q cols scaled by 0.125*log2(e) (exp2-domain softmax)
// MODE 1: out bf16 vt[(b*16+h)*64+d][2048]
// MODE 2: out f32 d_out[4096,1024]
template <int MODE>
__global__ __launch_bounds__(256) void k_gemm(const u16* __restrict__ A, const u16* __restrict__ Bt,
                                              const float* __restrict__ b0, const float* __restrict__ b1,
                                              u16* __restrict__ outb, float* __restrict__ outf) {
  constexpr int K = 1024;
  __shared__ __align__(16) u16 As[128 * 64];
  __shared__ __align__(16) u16 Bs[128 * 64];
  const int tid = threadIdx.x, wid = tid >> 6, lane = tid & 63;
  const int lo = lane & 15, hi = lane >> 4;
  const int wr = wid >> 1, wc = wid & 1;
  const int bm = blockIdx.y, bn = blockIdx.x;
  const u16* Ab = A + (size_t)bm * 128 * K;
  const u16* Bb = Bt + (size_t)bn * 128 * K;
  const int sr = lane >> 3, sc = lane & 7;
  f32x4 acc[4][4] = {};
  for (int k0 = 0; k0 < K; k0 += 64) {
    __syncthreads();
#pragma unroll
    for (int i = 0; i < 4; ++i) {
      int r = wid * 32 + i * 8 + sr;
      int cs = sc ^ (r & 7);
      gld_lds16(Ab + (size_t)r * K + k0 + cs * 8, As + (wid * 32 + i * 8) * 64);
      gld_lds16(Bb + (size_t)r * K + k0 + cs * 8, Bs + (wid * 32 + i * 8) * 64);
    }
    __syncthreads();
#pragma unroll
    for (int ks = 0; ks < 2; ++ks) {
      bf16x8 af[4], bfr[4];
#pragma unroll
      for (int mt = 0; mt < 4; ++mt) {
        int r = wr * 64 + mt * 16 + lo;
        int c = (hi + 4 * ks) ^ (r & 7);
        af[mt] = *(const bf16x8*)(As + r * 64 + c * 8);
      }
#pragma unroll
      for (int nt = 0; nt < 4; ++nt) {
        int r = wc * 64 + nt * 16 + lo;
        int c = (hi + 4 * ks) ^ (r & 7);
        bfr[nt] = *(const bf16x8*)(Bs + r * 64 + c * 8);
      }
#pragma unroll
      for (int mt = 0; mt < 4; ++mt)
#pragma unroll
        for (int nt = 0; nt < 4; ++nt)
          acc[mt][nt] = __builtin_amdgcn_mfma_f32_16x16x32_bf16(af[mt], bfr[nt], acc[mt][nt], 0, 0, 0);
    }
  }
#pragma unroll
  for (int mt = 0; mt < 4; ++mt) {
#pragma unroll
    for (int nt = 0; nt < 4; ++nt) {
      const int i0 = bm * 128 + wr * 64 + mt * 16 + hi * 4;
      const int j = bn * 128 + wc * 64 + nt * 16 + lo;
#pragma unroll
      for (int rg = 0; rg < 4; ++rg) {
        const int i = i0 + rg;
        float v = acc[mt][nt][rg];
        if (MODE == 0) {
          v += (j < 1024) ? b0[j] : b1[j - 1024];
          if (j < 1024) v *= 0.18033688011112042f;  // (1/8)*log2(e): exp2-domain logits
          outb[(size_t)i * 2048 + j] = f2bf(v);
        } else if (MODE == 1) {
          v += b0[i];
          outb[(size_t)((j >> 11) * 1024 + i) * 2048 + (j & 2047)] = f2bf(v);
        } else {
          v += b0[j];
          outf[(size_t)i * 1024 + j] = v;
        }
      }
    }
  }
}

// ---------------- flash attention (32x32 MFMA, in-register P, t-split 2x) ----------------
// qk: [4096][2048] bf16 (Q cols pre-scaled by (1/8)log2e, K cols 1024..2047)
// vt: [(b*16+h)*64 + d][2048] bf16 (V transposed)
// ao: [4096][1024] bf16 concat output
// Block: 8 waves (512 thr). Waves 0-3: t in [0,1024); waves 4-7: t in [1024,2048).
// Wave (tg,qw) handles 32 q = qb*128 + qw*32 + (lane&31), 16 iters of 64 t.
// End: (m,l,O) pair-merge via LDS (buffers reused after last barrier).
// XCD swizzle: logical block = (hw%8)*64 + hw/8 -> each XCD owns 4 (b,h) K/V panels (L2-fit).
__global__ __launch_bounds__(512, 4) void k_attn(const u16* __restrict__ qk, const u16* __restrict__ vt,
                                                 u16* __restrict__ ao) {
  __shared__ __align__(16) u16 smem[32768];  // 64KB: K[tg][buf][4096] | V at +16384
  const int tid = threadIdx.x, wid = tid >> 6, lane = tid & 63;
  const int ql = lane & 31, Lh = lane >> 5;
  const int tg = wid >> 2, qw = wid & 3;
  const int logical = (blockIdx.x & 7) * 64 + (blockIdx.x >> 3);  // bijective XCD swizzle (512 = 8*64)
  const int qb = logical & 15, bh = logical >> 4;
  const int b = bh >> 4, h = bh & 15;
  const int qg = qb * 128 + qw * 32 + ql;  // q within this batch's sequence

  u16* const Kbase = smem + tg * 2 * 4096;
  u16* const Vbase = smem + 16384 + tg * 2 * 4096;

  // Q as B-frags (lane: n=q=ql, k=d=Lh*8+e per 16-k step), kd=0..3
  bf16x8 qB[4];
  const u16* qrow = qk + (size_t)(b * 2048 + qg) * 2048 + h * 64;
#pragma unroll
  for (int kd = 0; kd < 4; ++kd) qB[kd] = *(const bf16x8*)(qrow + kd * 16 + Lh * 8);

  const u16* Kg = qk + 1024 + (size_t)b * 2048 * 2048 + (size_t)tg * 1024 * 2048 + h * 64;  // + t*2048
  const u16* Vg = vt + (size_t)bh * 64 * 2048 + tg * 1024;                                  // + d*2048 + t
  const int sr = lane >> 3, sc = lane & 7;

  f32x16 acco[2] = {};
  float m_run = -1e30f, l_part = 0.f;

  // stage tile 0 of this t-group
#pragma unroll
  for (int i = 0; i < 2; ++i) {
    int r = qw * 16 + i * 8 + sr;
    int cs = sc ^ (r & 7);
    gld_lds16(Kg + (size_t)r * 2048 + cs * 8, Kbase + (qw * 16 + i * 8) * 64);
    gld_lds16(Vg + (size_t)r * 2048 + cs * 8, Vbase + (qw * 16 + i * 8) * 64);
  }

  for (int it = 0; it < 16; ++it) {
    __syncthreads();  // tile `it` staged (vmcnt(0) drained at barrier)
    if (it + 1 < 16) {
      const int t0 = (it + 1) * 64, bo2 = ((it + 1) & 1) * 4096;
#pragma unroll
      for (int i = 0; i < 2; ++i) {
        int r = qw * 16 + i * 8 + sr;
        int cs = sc ^ (r & 7);
        gld_lds16(Kg + (size_t)(t0 + r) * 2048 + cs * 8, Kbase + bo2 + (qw * 16 + i * 8) * 64);
        gld_lds16(Vg + (size_t)r * 2048 + t0 + cs * 8, Vbase + bo2 + (qw * 16 + i * 8) * 64);
      }
    }
    const u16* Kb = Kbase + (it & 1) * 4096;
    const u16* Vb = Vbase + (it & 1) * 4096;

    // S^T = K * Q : C[m=t][n=q]; lane holds 16 t-values per 32-t tile for q=ql
    f32x16 accs[2] = {};
#pragma unroll
    for (int kd = 0; kd < 4; ++kd) {
      int cg = 2 * kd + Lh;  // 8-elem col-group in d
#pragma unroll
      for (int tt = 0; tt < 2; ++tt) {
        int r = tt * 32 + ql;
        bf16x8 ka = *(const bf16x8*)(Kb + r * 64 + (cg ^ (r & 7)) * 8);
        accs[tt] = __builtin_amdgcn_mfma_f32_32x32x16_bf16(ka, qB[kd], accs[tt], 0, 0, 0);
      }
    }

    // V A-frags loaded early: DS latency hides under softmax VALU
    bf16x8 vf[2][4];
#pragma unroll
    for (int dt = 0; dt < 2; ++dt)
#pragma unroll
      for (int kt = 0; kt < 4; ++kt) {
        int r = dt * 32 + ql;
        int cg = 2 * kt + Lh;
        vf[dt][kt] = *(const bf16x8*)(Vb + r * 64 + (cg ^ (r & 7)) * 8);
      }

    // lane-local max tree (depth ~5)
    float t8[8];
#pragma unroll
    for (int m = 0; m < 8; ++m)
      t8[m] = fmaxf(fmaxf(accs[0][2 * m], accs[0][2 * m + 1]),
                    fmaxf(accs[1][2 * m], accs[1][2 * m + 1]));
    float mx = fmaxf(fmaxf(fmaxf(t8[0], t8[1]), fmaxf(t8[2], t8[3])),
                     fmaxf(fmaxf(t8[4], t8[5]), fmaxf(t8[6], t8[7])));

    if (__any(mx > m_run + 8.f)) {  // rare after warm-up: defer-max
      float mxw = fmaxf(mx, __shfl_xor(mx, 32));
      float mnew = fmaxf(m_run, mxw);
      float al = ex2(m_run - mnew);
      m_run = mnew;
      l_part *= al;
      acco[0] *= al;
      acco[1] *= al;
    }

    // exp2 + pack P pairs; l accumulates lane-locally (combined at end)
    unsigned dw[2][8];
    float ls0 = 0.f, ls1 = 0.f;
#pragma unroll
    for (int tt = 0; tt < 2; ++tt)
#pragma unroll
      for (int m = 0; m < 8; ++m) {
        float p0 = ex2(accs[tt][2 * m] - m_run);
        float p1 = ex2(accs[tt][2 * m + 1] - m_run);
        if (m & 1) ls1 += p0 + p1; else ls0 += p0 + p1;
        dw[tt][m] = cvtpk(p0, p1);
      }
    l_part += ls0 + ls1;

    // O^T += V^T * P : per k-step, B-frag from 2 permlane32_swap
#pragma unroll
    for (int kt = 0; kt < 4; ++kt) {
      const int tt = kt >> 1, c = kt & 1;
      u32x2 s0 = __builtin_amdgcn_permlane32_swap(dw[tt][4 * c + 0], dw[tt][4 * c + 2], false, false);
      u32x2 s1 = __builtin_amdgcn_permlane32_swap(dw[tt][4 * c + 1], dw[tt][4 * c + 3], false, false);
      union { unsigned u[4]; bf16x8 v; } pb;
      pb.u[0] = s0[0]; pb.u[1] = s1[0]; pb.u[2] = s0[1]; pb.u[3] = s1[1];
#pragma unroll
      for (int dt = 0; dt < 2; ++dt)
        acco[dt] = __builtin_amdgcn_mfma_f32_32x32x16_bf16(vf[dt][kt], pb.v, acco[dt], 0, 0, 0);
    }
  }

  // ---- pair merge across t-groups (LDS reused after final barrier) ----
  float lp = l_part + __shfl_xor(l_part, 32);  // per-q l for this t-half
  __syncthreads();                             // all K/V reads done; smem reusable
  float* Om = (float*)smem;                    // [4 qw][32 q][68 pitch] f32 = 34816 B
  float* Ml = (float*)(smem + 17408);          // 128 f32
  float* Ll = (float*)(smem + 17664);          // 128 f32

  if (tg == 1) {
#pragma unroll
    for (int dt = 0; dt < 2; ++dt)
#pragma unroll
      for (int g = 0; g < 4; ++g) {
        f32x4 w = { acco[dt][4 * g + 0], acco[dt][4 * g + 1],
                    acco[dt][4 * g + 2], acco[dt][4 * g + 3] };
        *(f32x4*)(Om + (qw * 32 + ql) * 68 + dt * 32 + g * 8 + Lh * 4) = w;
      }
    if (Lh == 0) { Ml[qw * 32 + ql] = m_run; Ll[qw * 32 + ql] = lp; }
  }
  __syncthreads();
  if (tg == 0) {
    const float m1 = Ml[qw * 32 + ql], l1 = Ll[qw * 32 + ql];
    const float ms = fmaxf(m_run, m1);
    const float a0 = ex2(m_run - ms), a1 = ex2(m1 - ms);
    const float inv = 1.f / (lp * a0 + l1 * a1);
    u16* orow = ao + (size_t)(b * 2048 + qg) * 1024 + h * 64;
#pragma unroll
    for (int dt = 0; dt < 2; ++dt)
#pragma unroll
      for (int g = 0; g < 4; ++g) {
        f32x4 o1 = *(const f32x4*)(Om + (qw * 32 + ql) * 68 + dt * 32 + g * 8 + Lh * 4);
        float o0f = (acco[dt][4 * g + 0] * a0 + o1[0] * a1) * inv;
        float o1f = (acco[dt][4 * g + 1] * a0 + o1[1] * a1) * inv;
        float o2f = (acco[dt][4 * g + 2] * a0 + o1[2] * a1) * inv;
        float o3f = (acco[dt][4 * g + 3] * a0 + o1[3] * a1) * inv;
        uint2 w; w.x = cvtpk(o0f, o1f); w.y = cvtpk(o2f, o3f);
        *(uint2*)(orow + dt * 32 + g * 8 + Lh * 4) = w;
      }
  }
}

// ---------------- launch ----------------
extern "C" void kernel_launch(void* const* d_in, const int* in_sizes, int n_in,
                              void* d_out, int out_size, void* d_ws, size_t ws_size,
                              hipStream_t stream) {
  const float* x  = (const float*)d_in[0];
  const float* Wq = (const float*)d_in[1];
  const float* bq = (const float*)d_in[2];
  const float* Wk = (const float*)d_in[3];
  const float* bk = (const float*)d_in[4];
  const float* Wv = (const float*)d_in[5];
  const float* bv = (const float*)d_in[6];
  const float* Wo = (const float*)d_in[7];
  const float* bo = (const float*)d_in[8];
  float* out = (float*)d_out;

  char* ws = (char*)d_ws;
  u16* xb   = (u16*)(ws);                        // 8 MB  x bf16 [4096][1024]
  u16* wqkt = (u16*)(ws + (8u << 20));           // 4 MB  [2048][1024]
  u16* wvt  = (u16*)(ws + (12u << 20));          // 2 MB  [1024][1024]
  u16* wot  = (u16*)(ws + (14u << 20));          // 2 MB  [1024][1024]
  u16* qk   = (u16*)(ws + (16u << 20));          // 16 MB [4096][2048]
  u16* vt   = (u16*)(ws + (32u << 20));          // 8 MB  [2*16*64][2048]
  u16* aob  = (u16*)(ws + (40u << 20));          // 8 MB  [4096][1024]   (48 MB total)

  k_cast_x<<<4096, 256, 0, stream>>>(x, xb);
  k_prep_w<<<1024, 256, 0, stream>>>(Wq, Wk, Wv, Wo, wqkt, wvt, wot);
  k_gemm<0><<<dim3(16, 32), 256, 0, stream>>>(xb, wqkt, bq, bk, qk, nullptr);
  k_gemm<1><<<dim3(32, 8), 256, 0, stream>>>(wvt, xb, bv, nullptr, vt, nullptr);
  k_attn<<<512, 512, 0, stream>>>(qk, vt, aob);
  k_gemm<2><<<dim3(8, 32), 256, 0, stream>>>(aob, wot, bo, nullptr, nullptr, out);
}

// Round 5
// 135.095 us; speedup vs baseline: 1.1258x; 1.1258x over previous
//
#include <hip/hip_runtime.h>
#include <hip/hip_bf16.h>

#define DEV __device__ __forceinline__

typedef unsigned short u16;
typedef __attribute__((ext_vector_type(8))) short bf16x8;
typedef __attribute__((ext_vector_type(4))) float f32x4;
typedef __attribute__((ext_vector_type(16))) float f32x16;
typedef __attribute__((ext_vector_type(4))) unsigned short us4;
typedef __attribute__((ext_vector_type(2))) unsigned u32x2;

DEV void gld_lds16(const void* g, void* l) {
  __builtin_amdgcn_global_load_lds((const __attribute__((address_space(1))) void*)g,
                                   (__attribute__((address_space(3))) void*)l, 16, 0, 0);
}

DEV u16 f2bf(float x) {  // RNE f32->bf16 (inputs finite)
  union { float f; unsigned u; } v; v.f = x;
  unsigned r = v.u + 0x7FFFu + ((v.u >> 16) & 1u);
  return (u16)(r >> 16);
}

DEV float ex2(float x) {  // 2^x
  float r; asm("v_exp_f32 %0, %1" : "=v"(r) : "v"(x)); return r;
}

DEV unsigned cvtpk(float a, float b) {  // [bf16(b)<<16 | bf16(a)]
  unsigned r; asm("v_cvt_pk_bf16_f32 %0, %1, %2" : "=v"(r) : "v"(a), "v"(b)); return r;
}

// ---------------- prep: cast x to bf16 ----------------
__global__ __launch_bounds__(256) void k_cast_x(const float* __restrict__ x, u16* __restrict__ xb) {
  int i = (blockIdx.x * 256 + threadIdx.x) * 4;
  const float4 v = *(const float4*)(x + i);
  us4 o; o.x = f2bf(v.x); o.y = f2bf(v.y); o.z = f2bf(v.z); o.w = f2bf(v.w);
  *(us4*)(xb + i) = o;
}

// ---------------- prep: transpose-pack weights to bf16 ----------------
__global__ __launch_bounds__(256) void k_prep_w(const float* __restrict__ Wq, const float* __restrict__ Wk,
                                                const float* __restrict__ Wv, const float* __restrict__ Wo,
                                                u16* __restrict__ wqkt, u16* __restrict__ wvt,
                                                u16* __restrict__ wot) {
  __shared__ float t[64][65];
  const int bb = blockIdx.x, tid = threadIdx.x;
  const float* src; u16* dst; int src_ld, dst_row0, dst_col0;
  if (bb < 768) {
    int which = bb >> 8, h = (bb >> 4) & 15, m0 = (bb & 15) * 64;
    const float* W = which == 0 ? Wq : (which == 1 ? Wk : Wv);
    src = W + h * 65536 + m0 * 64; src_ld = 64;
    dst = (which == 2) ? wvt : (wqkt + (which == 1 ? (1024 * 1024) : 0));
    dst_row0 = h * 64; dst_col0 = m0;
  } else {
    int t2 = bb - 768, mt = t2 >> 4, nt = t2 & 15;
    src = Wo + (size_t)(mt * 64) * 1024 + nt * 64; src_ld = 1024;
    dst = wot; dst_row0 = nt * 64; dst_col0 = mt * 64;
  }
  {
    int r = tid >> 2, c0 = (tid & 3) * 16;
    const float* s = src + (size_t)r * src_ld + c0;
#pragma unroll
    for (int q = 0; q < 4; ++q) {
      float4 v = *(const float4*)(s + q * 4);
      t[r][c0 + q * 4 + 0] = v.x; t[r][c0 + q * 4 + 1] = v.y;
      t[r][c0 + q * 4 + 2] = v.z; t[r][c0 + q * 4 + 3] = v.w;
    }
  }
  __syncthreads();
  {
    int d = tid >> 2, mb = (tid & 3) * 16;
    bf16x8 v0, v1;
#pragma unroll
    for (int e = 0; e < 8; ++e) {
      v0[e] = (short)f2bf(t[mb + e][d]);
      v1[e] = (short)f2bf(t[mb + 8 + e][d]);
    }
    u16* dp = dst + (size_t)(dst_row0 + d) * 1024 + dst_col0 + mb;
    *(bf16x8*)(dp) = v0;
    *(bf16x8*)(dp + 8) = v1;
  }
}

// ---------------- GEMM: C[M,N] = A[M,K] x Bt[N,K]^T (+bias, epilogue by MODE) ----------------
// Double-buffered, ONE raw barrier per K-step; next-tile gld_lds overlap compute (T3 2-phase).
// MODE 0: out bf16 qk[4096,2048]; Q cols scaled by 0.125*log2(e) (exp2-domain softmax)
// MODE 1: out bf16 vt[(b*16+h)*64+d][2048]
// MODE 2: out f32 d_out[4096,1024]
template <int MODE>
__global__ __launch_bounds__(256) void k_gemm(const u16* __restrict__ A, const u16* __restrict__ Bt,
                                              const float* __restrict__ b0, const float* __restrict__ b1,
                                              u16* __restrict__ outb, float* __restrict__ outf) {
  constexpr int K = 1024;
  __shared__ __align__(16) u16 As[2][128 * 64];
  __shared__ __align__(16) u16 Bs[2][128 * 64];
  const int tid = threadIdx.x, wid = tid >> 6, lane = tid & 63;
  const int lo = lane & 15, hi = lane >> 4;
  const int wr = wid >> 1, wc = wid & 1;
  const int bm = blockIdx.y, bn = blockIdx.x;
  const u16* Ab = A + (size_t)bm * 128 * K;
  const u16* Bb = Bt + (size_t)bn * 128 * K;
  const int sr = lane >> 3, sc = lane & 7;
  f32x4 acc[4][4] = {};

  // stage tile 0 -> buf 0
#pragma unroll
  for (int i = 0; i < 4; ++i) {
    int r = wid * 32 + i * 8 + sr;
    int cs = sc ^ (r & 7);
    gld_lds16(Ab + (size_t)r * K + cs * 8, &As[0][(wid * 32 + i * 8) * 64]);
    gld_lds16(Bb + (size_t)r * K + cs * 8, &Bs[0][(wid * 32 + i * 8) * 64]);
  }

  int cur = 0;
  for (int kt = 0; kt < 16; ++kt) {
    // tile kt resident after this wait+barrier; all waves past tile kt-1 reads
    asm volatile("s_waitcnt vmcnt(0)" ::: "memory");
    __builtin_amdgcn_s_barrier();
    if (kt + 1 < 16) {  // stage tile kt+1 into buf^1; latency hides under compute below
      const int k0 = (kt + 1) * 64;
#pragma unroll
      for (int i = 0; i < 4; ++i) {
        int r = wid * 32 + i * 8 + sr;
        int cs = sc ^ (r & 7);
        gld_lds16(Ab + (size_t)r * K + k0 + cs * 8, &As[cur ^ 1][(wid * 32 + i * 8) * 64]);
        gld_lds16(Bb + (size_t)r * K + k0 + cs * 8, &Bs[cur ^ 1][(wid * 32 + i * 8) * 64]);
      }
    }
#pragma unroll
    for (int ks = 0; ks < 2; ++ks) {
      bf16x8 af[4], bfr[4];
#pragma unroll
      for (int mt = 0; mt < 4; ++mt) {
        int r = wr * 64 + mt * 16 + lo;
        int c = (hi + 4 * ks) ^ (r & 7);
        af[mt] = *(const bf16x8*)(&As[cur][r * 64 + c * 8]);
      }
#pragma unroll
      for (int nt = 0; nt < 4; ++nt) {
        int r = wc * 64 + nt * 16 + lo;
        int c = (hi + 4 * ks) ^ (r & 7);
        bfr[nt] = *(const bf16x8*)(&Bs[cur][r * 64 + c * 8]);
      }
#pragma unroll
      for (int mt = 0; mt < 4; ++mt)
#pragma unroll
        for (int nt = 0; nt < 4; ++nt)
          acc[mt][nt] = __builtin_amdgcn_mfma_f32_16x16x32_bf16(af[mt], bfr[nt], acc[mt][nt], 0, 0, 0);
    }
    cur ^= 1;
  }
#pragma unroll
  for (int mt = 0; mt < 4; ++mt) {
#pragma unroll
    for (int nt = 0; nt < 4; ++nt) {
      const int i0 = bm * 128 + wr * 64 + mt * 16 + hi * 4;
      const int j = bn * 128 + wc * 64 + nt * 16 + lo;
#pragma unroll
      for (int rg = 0; rg < 4; ++rg) {
        const int i = i0 + rg;
        float v = acc[mt][nt][rg];
        if (MODE == 0) {
          v += (j < 1024) ? b0[j] : b1[j - 1024];
          if (j < 1024) v *= 0.18033688011112042f;  // (1/8)*log2(e): exp2-domain logits
          outb[(size_t)i * 2048 + j] = f2bf(v);
        } else if (MODE == 1) {
          v += b0[i];
          outb[(size_t)((j >> 11) * 1024 + i) * 2048 + (j & 2047)] = f2bf(v);
        } else {
          v += b0[j];
          outf[(size_t)i * 1024 + j] = v;
        }
      }
    }
  }
}

// ---------------- flash attention (32x32 MFMA, in-register P, 3-buf counted-vmcnt pipeline) ----------------
// qk: [4096][2048] bf16 (Q cols pre-scaled by (1/8)log2e, K cols 1024..2047)
// vt: [(b*16+h)*64 + d][2048] bf16 (V transposed)
// ao: [4096][1024] bf16 concat output
// Block: 4 waves x 32 q = 128 q. Wave computes S^T = mfma32(K, Q): lane owns q = lane&31.
// Pipeline: 3 LDS buffers, prefetch 2 tiles ahead; per iter s_waitcnt vmcnt(4) + raw s_barrier
// keeps tile it+1's 4 loads in flight across the barrier (T4 counted vmcnt) -> load latency
// gets 2 compute phases to hide. 48KB LDS -> 3 blocks/CU.
__global__ __launch_bounds__(256, 3) void k_attn(const u16* __restrict__ qk, const u16* __restrict__ vt,
                                                 u16* __restrict__ ao) {
  __shared__ __align__(16) u16 Kl[3][64 * 64];
  __shared__ __align__(16) u16 Vl[3][64 * 64];
  const int tid = threadIdx.x, wid = tid >> 6, lane = tid & 63;
  const int ql = lane & 31, Lh = lane >> 5;
  const int qb = blockIdx.x & 15, bh = blockIdx.x >> 4;
  const int b = bh >> 4, h = bh & 15;
  const int qg = qb * 128 + wid * 32 + ql;  // q within this batch's sequence

  // Q as B-frags (lane: n=q=ql, k=d=Lh*8+e per 16-k step), kd=0..3
  bf16x8 qB[4];
  const u16* qrow = qk + (size_t)(b * 2048 + qg) * 2048 + h * 64;
#pragma unroll
  for (int kd = 0; kd < 4; ++kd) qB[kd] = *(const bf16x8*)(qrow + kd * 16 + Lh * 8);

  const u16* Kg = qk + 1024 + (size_t)b * 2048 * 2048 + h * 64;  // + t*2048
  const u16* Vg = vt + (size_t)bh * 64 * 2048;                   // + d*2048 + t
  const int sr = lane >> 3, sc = lane & 7;

  f32x16 acco[2] = {};
  float m_run = -1e30f, l_part = 0.f;

  // stage tiles 0,1 (4 gld_lds each per wave: 2 K + 2 V)
#pragma unroll
  for (int t = 0; t < 2; ++t)
#pragma unroll
    for (int i = 0; i < 2; ++i) {
      int r = wid * 16 + i * 8 + sr;
      int cs = sc ^ (r & 7);
      gld_lds16(Kg + (size_t)(t * 64 + r) * 2048 + cs * 8, &Kl[t][(wid * 16 + i * 8) * 64]);
      gld_lds16(Vg + (size_t)r * 2048 + t * 64 + cs * 8, &Vl[t][(wid * 16 + i * 8) * 64]);
    }

  int cur = 0;
  for (int it = 0; it < 32; ++it) {
    // tile `it` done (leave tile it+1's 4 loads in flight); barrier syncs all waves
    if (it < 31) asm volatile("s_waitcnt vmcnt(4)" ::: "memory");
    else         asm volatile("s_waitcnt vmcnt(0)" ::: "memory");
    __builtin_amdgcn_s_barrier();
    if (it + 2 < 32) {  // stage tile it+2 into buffer holding tile it-1 (reads done pre-barrier)
      int sb = cur + 2; if (sb >= 3) sb -= 3;
      const int t0 = (it + 2) * 64;
#pragma unroll
      for (int i = 0; i < 2; ++i) {
        int r = wid * 16 + i * 8 + sr;
        int cs = sc ^ (r & 7);
        gld_lds16(Kg + (size_t)(t0 + r) * 2048 + cs * 8, &Kl[sb][(wid * 16 + i * 8) * 64]);
        gld_lds16(Vg + (size_t)r * 2048 + t0 + cs * 8, &Vl[sb][(wid * 16 + i * 8) * 64]);
      }
    }
    const u16* Kb = Kl[cur];
    const u16* Vb = Vl[cur];

    // S^T = K * Q : C[m=t][n=q]; lane holds 16 t-values per 32-t tile for q=ql
    f32x16 accs[2] = {};
#pragma unroll
    for (int kd = 0; kd < 4; ++kd) {
      int cg = 2 * kd + Lh;  // 8-elem col-group in d
#pragma unroll
      for (int tt = 0; tt < 2; ++tt) {
        int r = tt * 32 + ql;
        bf16x8 ka = *(const bf16x8*)(Kb + r * 64 + ((cg ^ (r & 7)) * 8));
        accs[tt] = __builtin_amdgcn_mfma_f32_32x32x16_bf16(ka, qB[kd], accs[tt], 0, 0, 0);
      }
    }

    // V A-frags loaded early: DS latency hides under softmax VALU
    bf16x8 vf[2][4];
#pragma unroll
    for (int dt = 0; dt < 2; ++dt)
#pragma unroll
      for (int kt = 0; kt < 4; ++kt) {
        int r = dt * 32 + ql;
        int cg = 2 * kt + Lh;
        vf[dt][kt] = *(const bf16x8*)(Vb + r * 64 + ((cg ^ (r & 7)) * 8));
      }

    // lane-local max tree (depth ~5)
    float t8[8];
#pragma unroll
    for (int m = 0; m < 8; ++m)
      t8[m] = fmaxf(fmaxf(accs[0][2 * m], accs[0][2 * m + 1]),
                    fmaxf(accs[1][2 * m], accs[1][2 * m + 1]));
    float mx = fmaxf(fmaxf(fmaxf(t8[0], t8[1]), fmaxf(t8[2], t8[3])),
                     fmaxf(fmaxf(t8[4], t8[5]), fmaxf(t8[6], t8[7])));

    if (__any(mx > m_run + 8.f)) {  // rare after warm-up: defer-max
      float mxw = fmaxf(mx, __shfl_xor(mx, 32));
      float mnew = fmaxf(m_run, mxw);
      float al = ex2(m_run - mnew);
      m_run = mnew;
      l_part *= al;
      acco[0] *= al;
      acco[1] *= al;
    }

    // exp2 + pack P pairs; l accumulates lane-locally (combined once at end)
    unsigned dw[2][8];
    float ls0 = 0.f, ls1 = 0.f;
#pragma unroll
    for (int tt = 0; tt < 2; ++tt)
#pragma unroll
      for (int m = 0; m < 8; ++m) {
        float p0 = ex2(accs[tt][2 * m] - m_run);
        float p1 = ex2(accs[tt][2 * m + 1] - m_run);
        if (m & 1) ls1 += p0 + p1; else ls0 += p0 + p1;
        dw[tt][m] = cvtpk(p0, p1);
      }
    l_part += ls0 + ls1;

    // O^T += V^T * P : per k-step, B-frag from 2 permlane32_swap
#pragma unroll
    for (int kt = 0; kt < 4; ++kt) {
      const int tt = kt >> 1, c = kt & 1;
      u32x2 s0 = __builtin_amdgcn_permlane32_swap(dw[tt][4 * c + 0], dw[tt][4 * c + 2], false, false);
      u32x2 s1 = __builtin_amdgcn_permlane32_swap(dw[tt][4 * c + 1], dw[tt][4 * c + 3], false, false);
      union { unsigned u[4]; bf16x8 v; } pb;
      pb.u[0] = s0[0]; pb.u[1] = s1[0]; pb.u[2] = s0[1]; pb.u[3] = s1[1];
#pragma unroll
      for (int dt = 0; dt < 2; ++dt)
        acco[dt] = __builtin_amdgcn_mfma_f32_32x32x16_bf16(vf[dt][kt], pb.v, acco[dt], 0, 0, 0);
    }

    cur = (cur == 2) ? 0 : cur + 1;
  }

  // epilogue: O[q][d], d = 32dt + 8g + 4Lh + (reg&3)
  float lsum = l_part + __shfl_xor(l_part, 32);
  float inv = 1.f / lsum;
  u16* orow = ao + (size_t)(b * 2048 + qg) * 1024 + h * 64;
#pragma unroll
  for (int dt = 0; dt < 2; ++dt)
#pragma unroll
    for (int g = 0; g < 4; ++g) {
      float o0 = acco[dt][4 * g + 0] * inv, o1 = acco[dt][4 * g + 1] * inv;
      float o2 = acco[dt][4 * g + 2] * inv, o3 = acco[dt][4 * g + 3] * inv;
      uint2 w; w.x = cvtpk(o0, o1); w.y = cvtpk(o2, o3);
      *(uint2*)(orow + dt * 32 + g * 8 + Lh * 4) = w;
    }
}

// ---------------- launch ----------------
extern "C" void kernel_launch(void* const* d_in, const int* in_sizes, int n_in,
                              void* d_out, int out_size, void* d_ws, size_t ws_size,
                              hipStream_t stream) {
  const float* x  = (const float*)d_in[0];
  const float* Wq = (const float*)d_in[1];
  const float* bq = (const float*)d_in[2];
  const float* Wk = (const float*)d_in[3];
  const float* bk = (const float*)d_in[4];
  const float* Wv = (const float*)d_in[5];
  const float* bv = (const float*)d_in[6];
  const float* Wo = (const float*)d_in[7];
  const float* bo = (const float*)d_in[8];
  float* out = (float*)d_out;

  char* ws = (char*)d_ws;
  u16* xb   = (u16*)(ws);                        // 8 MB  x bf16 [4096][1024]
  u16* wqkt = (u16*)(ws + (8u << 20));           // 4 MB  [2048][1024]
  u16* wvt  = (u16*)(ws + (12u << 20));          // 2 MB  [1024][1024]
  u16* wot  = (u16*)(ws + (14u << 20));          // 2 MB  [1024][1024]
  u16* qk   = (u16*)(ws + (16u << 20));          // 16 MB [4096][2048]
  u16* vt   = (u16*)(ws + (32u << 20));          // 8 MB  [2*16*64][2048]
  u16* aob  = (u16*)(ws + (40u << 20));          // 8 MB  [4096][1024]   (48 MB total)

  k_cast_x<<<4096, 256, 0, stream>>>(x, xb);
  k_prep_w<<<1024, 256, 0, stream>>>(Wq, Wk, Wv, Wo, wqkt, wvt, wot);
  k_gemm<0><<<dim3(16, 32), 256, 0, stream>>>(xb, wqkt, bq, bk, qk, nullptr);
  k_gemm<1><<<dim3(32, 8), 256, 0, stream>>>(wvt, xb, bv, nullptr, vt, nullptr);
  k_attn<<<512, 256, 0, stream>>>(qk, vt, aob);
  k_gemm<2><<<dim3(8, 32), 256, 0, stream>>>(aob, wot, bo, nullptr, nullptr, out);
}